// Round 1
// baseline (311.337 us; speedup 1.0000x reference)
//
#include <hip/hip_runtime.h>
#include <math.h>

// Problem: log2 quantization (n_bits=4, per-channel symmetric) of x[4096][11008] fp32.
// out = sign(x) * 2^clamp(rint(log2(|x|+eps)), zero, zero+7), 0 if below zero,
// where zero = floor(log2(max_row|x| + eps) + 0.5) - 7.

#define NROW 4096
#define D    11008
#define D4   (D / 4)       // 2752, exact
#define EPSF 1e-32f
#define NTHREADS 256

__device__ __forceinline__ float quant_one(float v, float zero) {
    float a  = fabsf(v);
    float xl = log2f(a + EPSF);          // x_log (f32, matches reference)
    float xi = rintf(xl);                // round half-even == jnp.round
    float c1 = fmaxf(xi - zero, -1.0f);  // x_c1
    float c  = fminf(c1 - 8.0f, -1.0f);  // x_c (half_levels = 8)
    float q  = exp2f(c + 8.0f + zero);   // exact: integer-valued exponent
    if (c1 <= -1.0f) q = 0.0f;           // zero flag
    return copysignf(q, v);              // * sign(x); q==0 when x==0
}

__global__ __launch_bounds__(NTHREADS)
void log2_quant_kernel(const float* __restrict__ x, float* __restrict__ out) {
    __shared__ float row[D];             // 44032 B
    __shared__ float wmax[NTHREADS / 64];

    const int r   = blockIdx.x;
    const int tid = threadIdx.x;
    const float4* __restrict__ xr = (const float4*)(x + (size_t)r * D);
    float4* __restrict__ outr     = (float4*)(out + (size_t)r * D);
    float4* rowv                  = (float4*)row;

    // Phase 1: stage row into LDS, track per-thread max |x|.
    float m = 0.0f;
    for (int i = tid; i < D4; i += NTHREADS) {
        float4 v = xr[i];
        rowv[i] = v;
        m = fmaxf(m, fmaxf(fmaxf(fabsf(v.x), fabsf(v.y)),
                           fmaxf(fabsf(v.z), fabsf(v.w))));
    }

    // Wave-level max reduce (64 lanes).
    #pragma unroll
    for (int off = 32; off > 0; off >>= 1)
        m = fmaxf(m, __shfl_down(m, off, 64));

    const int lane = tid & 63;
    const int wid  = tid >> 6;
    if (lane == 0) wmax[wid] = m;
    __syncthreads();

    float xmax = fmaxf(fmaxf(wmax[0], wmax[1]), fmaxf(wmax[2], wmax[3]));

    // find_params: max_val = floor(log2(xmax + eps) + 0.5); zero = max_val - 7
    float max_val = floorf(log2f(xmax + EPSF) + 0.5f);
    float zero    = max_val - 7.0f;

    // Phase 2: quantize from LDS (same thread wrote these slots; barrier above
    // already covers the wmax dependency).
    for (int i = tid; i < D4; i += NTHREADS) {
        float4 v = rowv[i];
        float4 o;
        o.x = quant_one(v.x, zero);
        o.y = quant_one(v.y, zero);
        o.z = quant_one(v.z, zero);
        o.w = quant_one(v.w, zero);
        outr[i] = o;
    }
}

extern "C" void kernel_launch(void* const* d_in, const int* in_sizes, int n_in,
                              void* d_out, int out_size, void* d_ws, size_t ws_size,
                              hipStream_t stream) {
    const float* x = (const float*)d_in[0];
    float* out     = (float*)d_out;
    // n_bits (d_in[1]) is fixed at 4 per setup_inputs(); hard-coded above.
    log2_quant_kernel<<<NROW, NTHREADS, 0, stream>>>(x, out);
}